// Round 2
// baseline (280.087 us; speedup 1.0000x reference)
//
#include <hip/hip_runtime.h>
#include <hip/hip_bf16.h>

typedef __bf16 bf16x4 __attribute__((ext_vector_type(4)));
typedef __bf16 bf16x8 __attribute__((ext_vector_type(8)));
typedef float  f32x4  __attribute__((ext_vector_type(4)));
typedef float  f32x16 __attribute__((ext_vector_type(16)));

#define MFMA32(a,b,c) __builtin_amdgcn_mfma_f32_32x32x16_bf16((a),(b),(c),0,0,0)
#define MFMA16(a,b,c) __builtin_amdgcn_mfma_f32_16x16x32_bf16((a),(b),(c),0,0,0)

// TT shapes: INP_MODES [4,8,8,4], OUT_MODES [8,8,8,8], RANKS [1,8,8,8,1]
// Per (b, m0):
//   step0 (VALU): h0[k=(r1*8+n1)][col=(n2*4+n3)] computed DIRECTLY into the
//                 32x32 MFMA B-fragment registers (no LDS round trip).
//   step1 (MFMA 32x32x16): D1[(m1*8+r2)][(n2*4+n3)] = W1[64x64] @ h0
//   step2 (MFMA 32x32x16): D2[(m2*8+r3)][(n3*8+m1)] = W2[64x64] @ h1
//   step3 (MFMA 16x16x32): D3[m3(pad16)][(m2*8+m1)] = W3[16x32] @ h2 -> y
// 32x32 layouts: A[m=lane&31][k=(lane>>5)*8+j]; B[k][n=lane&31];
//                D[row=(reg&3)+8*(reg>>2)+4*(lane>>5)][col=lane&31] (measured)
// LDS: per-wave h1[col 32][k 64], h2[col 64][k 32], bf16, XOR-swizzled:
//   physical 16B-block = logical_kblock ^ low-bits(col) -> all accesses hit
//   the 32-bank phase floor (conflict-free).

__global__ __launch_bounds__(256, 3) void tt_kernel(
    const float* __restrict__ x,  const float* __restrict__ c0,
    const float* __restrict__ c1, const float* __restrict__ c2,
    const float* __restrict__ c3, const float* __restrict__ bias,
    float* __restrict__ y)
{
    __shared__ __align__(16) __bf16 h1s[4 * 2048];
    __shared__ __align__(16) __bf16 h2s[4 * 2048];
    __shared__ float w0s[256];

    const int tid  = threadIdx.x;
    const int wid  = tid >> 6;
    const int lane = tid & 63;
    const int hh   = lane >> 5;   // 32x32 MFMA k-half
    const int c32  = lane & 31;   // 32x32 MFMA row/col id
    const int g    = lane >> 4;   // 16x16 MFMA quad
    const int l    = lane & 15;

    if (tid < 256) w0s[tid] = c0[tid];
    __syncthreads();  // only barrier in the kernel

    __bf16* h1 = &h1s[wid * 2048];
    __bf16* h2 = &h2s[wid * 2048];

    // ---- persistent A-operand weight fragments ----
    // W1 rows=(m1*8+r2), k=(r1*8+n1): c1[r1][m1][r2][n1]
    // W2 rows=(m2*8+r3), k=(n2*8+r2): c2[r2][m2][r3][n2]
    // W3 rows=m3 (pad16), k=(n3*8+r3): c3[r3][m3][0][n3]
    bf16x8 w1f[2][4], w2f[2][4], w3f;
    const int rowoff = (c32 >> 3) * 64 + (c32 & 7) * 8;  // m-part*64 + r-part*8
    #pragma unroll
    for (int v = 0; v < 2; ++v) {
      #pragma unroll
      for (int t = 0; t < 4; ++t) {
        const int kq = t * 2 + hh;          // k octet: r1 (W1) / n2 (W2)
        const int rb = v * 256 + rowoff;
        #pragma unroll
        for (int j = 0; j < 8; ++j) {
          w1f[v][t][j] = (__bf16)c1[kq * 512 + rb + j];
          w2f[v][t][j] = (__bf16)c2[j * 512 + rb + kq];
        }
      }
    }
    #pragma unroll
    for (int j = 0; j < 8; ++j)
      w3f[j] = (l < 8) ? (__bf16)c3[j * 32 + l * 4 + g] : (__bf16)0.0f;

    const int gw = (blockIdx.x * 256 + tid) >> 6;   // 0..4095

    for (int bb = 0; bb < 2; ++bb) {
      const int b = gw + bb * 4096;
      const float* xb = x + (size_t)b * 1024 + c32;
      float xr[32];  // xr[n0*8+n1] = x[b][n0*256 + n1*32 + c32]
      #pragma unroll
      for (int n0 = 0; n0 < 4; ++n0)
        #pragma unroll
        for (int n1 = 0; n1 < 8; ++n1)
          xr[n0 * 8 + n1] = xb[n0 * 256 + n1 * 32];

      for (int m0 = 0; m0 < 8; ++m0) {
        // ---- step0: compute h0 B-fragments in registers ----
        // bfr[t][j] = h0[k=t*16+hh*8+j][c32], r1 = t*2+hh, n1 = j
        bf16x8 bfr[4];
        #pragma unroll
        for (int t = 0; t < 4; ++t) {
          const f32x4 w0 = *(const f32x4*)&w0s[m0 * 32 + (t * 2 + hh) * 4];
          #pragma unroll
          for (int j = 0; j < 8; ++j) {
            float a = w0[0] * xr[j]      + w0[1] * xr[8 + j]
                    + w0[2] * xr[16 + j] + w0[3] * xr[24 + j];
            bfr[t][j] = (__bf16)a;
          }
        }

        // ---- step1: 2 row-tiles x 4 k-tiles of 32x32x16 ----
        f32x16 acc0 = {}, acc1 = {};
        #pragma unroll
        for (int t = 0; t < 4; ++t) {
          acc0 = MFMA32(w1f[0][t], bfr[t], acc0);
          acc1 = MFMA32(w1f[1][t], bfr[t], acc1);
        }
        // D1 row = v*32 + 4*hh + i + 8*q (reg=q*4+i) -> m1=v*4+q, r2=4*hh+i
        // h1[col2=n3*8+m1][k2=n2*8+r2], n2=c32>>2, n3=c32&3; swizzle kb^=col2&7
        #pragma unroll
        for (int v = 0; v < 2; ++v) {
          const f32x16 A = v ? acc1 : acc0;
          #pragma unroll
          for (int q = 0; q < 4; ++q) {
            bf16x4 o;
            #pragma unroll
            for (int i = 0; i < 4; ++i) o[i] = (__bf16)A[q * 4 + i];
            const int col2 = (c32 & 3) * 8 + v * 4 + q;
            const int kb   = (c32 >> 2) ^ (v * 4 + q);
            *(bf16x4*)&h1[col2 * 64 + kb * 8 + hh * 4] = o;
          }
        }

        // ---- step2 ----
        f32x16 acc2 = {}, acc3 = {};
        #pragma unroll
        for (int t = 0; t < 4; ++t) {
          const bf16x8 b2 =
            *(const bf16x8*)&h1[c32 * 64 + ((t * 2 + hh) ^ (c32 & 7)) * 8];
          acc2 = MFMA32(w2f[0][t], b2, acc2);
          acc3 = MFMA32(w2f[1][t], b2, acc3);
        }
        // D2 row -> m2=v*4+q, r3=4*hh+i; col=c32 -> n3=c32>>3, m1=c32&7
        // h2[col3=m2*8+m1][k3=n3*8+r3]; swizzle kb ^= (col3>>1)&3
        #pragma unroll
        for (int v = 0; v < 2; ++v) {
          const f32x16 A = v ? acc3 : acc2;
          #pragma unroll
          for (int q = 0; q < 4; ++q) {
            bf16x4 o;
            #pragma unroll
            for (int i = 0; i < 4; ++i) o[i] = (__bf16)A[q * 4 + i];
            const int col3 = (v * 4 + q) * 8 + (c32 & 7);
            const int kb   = (c32 >> 3) ^ ((c32 >> 1) & 3);
            *(bf16x4*)&h2[col3 * 32 + kb * 8 + hh * 4] = o;
          }
        }

        // ---- step3: 16x16x32, rows 8..15 pad; bias + store ----
        const float* bslice = bias + m0 * 512;
        float* yb = y + (size_t)b * 4096 + m0 * 512;
        #pragma unroll
        for (int u = 0; u < 4; ++u) {
          const int col = u * 16 + l;
          const bf16x8 bf =
            *(const bf16x8*)&h2[col * 32 + (g ^ ((l >> 1) & 3)) * 8];
          f32x4 acc = {};
          acc = MFMA16(w3f, bf, acc);
          // D3 row = g*4+r = m3 (g<2); col = m2*8+m1; y off = m1*64+m2*8+m3
          if (g < 2) {
            const int off = (col & 7) * 64 + (col >> 3) * 8 + g * 4;
            const f32x4 bv = *(const f32x4*)&bslice[off];
            *(f32x4*)&yb[off] = acc + bv;
          }
        }
      }
    }
}

extern "C" void kernel_launch(void* const* d_in, const int* in_sizes, int n_in,
                              void* d_out, int out_size, void* d_ws, size_t ws_size,
                              hipStream_t stream) {
    const float* x    = (const float*)d_in[0];
    const float* c0   = (const float*)d_in[1];
    const float* c1   = (const float*)d_in[2];
    const float* c2   = (const float*)d_in[3];
    const float* c3   = (const float*)d_in[4];
    const float* bias = (const float*)d_in[5];
    float* yout = (float*)d_out;
    // 1024 blocks x 256 threads = 4096 waves x 2 batch elements = 8192
    tt_kernel<<<1024, 256, 0, stream>>>(x, c0, c1, c2, c3, bias, yout);
}

// Round 3
// 229.477 us; speedup vs baseline: 1.2205x; 1.2205x over previous
//
#include <hip/hip_runtime.h>
#include <hip/hip_bf16.h>

typedef __bf16 bf16x4 __attribute__((ext_vector_type(4)));
typedef __bf16 bf16x8 __attribute__((ext_vector_type(8)));
typedef float  f32x4  __attribute__((ext_vector_type(4)));
typedef float  f32x16 __attribute__((ext_vector_type(16)));

#define MFMA32(a,b,c) __builtin_amdgcn_mfma_f32_32x32x16_bf16((a),(b),(c),0,0,0)

// Merged-weight TT forward.
//   W01[m0][(m1*8+r2)][(n0*8+n1)] = sum_r1 c0[m0][r1*4+n0] * c1[(r1*8+m1)][(r2*8+n1)]
//   W23[(m2*8+m3)][(n2*32+n3*8+r2)] = sum_r3 c2[(r2*8+m2)][(r3*8+n2)] * c3[(r3*8+m3)][n3]
// Per 2-batch iter: Xt[col=(b^,n2n3)][k=(n0,n1)] in LDS; per m0-quad:
//   stage A: H[(m1 r2)][(n2n3)] = W01^(m0) @ Xt  (wave role: rt=row-tile, ct=batch)
//            -> Hb[col=(b^,m0^,m1)][k=(n2,n3,r2)]  (LDS, swizzled)
//   stage B: Y[(m2 m3)][(b^,m0^,m1)] = W23 @ Hb, K=256 -> y + bias
// 32x32x16 layouts (HW-validated in R1): A[m=lane&31][k=(lane>>5)*8+j],
//   B[k][n=lane&31], D[row=(reg&3)+8*(reg>>2)+4*(lane>>5)][col=lane&31].
// All LDS b128/b64 patterns XOR-swizzled to the 32-bank phase floor.

__global__ __launch_bounds__(256) void tt_kernel(
    const float* __restrict__ x,  const float* __restrict__ c0,
    const float* __restrict__ c1, const float* __restrict__ c2,
    const float* __restrict__ c3, const float* __restrict__ bias,
    float* __restrict__ y)
{
    __shared__ __align__(16) __bf16 w23l[16384];  // 32 KB, A-frag swizzled
    __shared__ __align__(16) __bf16 xt[2048];     //  4 KB
    __shared__ __align__(16) __bf16 hb[16384];    // 32 KB

    const int tid  = threadIdx.x;
    const int wid  = tid >> 6;
    const int lane = tid & 63;
    const int hh   = lane >> 5;   // MFMA k-half
    const int c32  = lane & 31;   // MFMA row/col id
    const int rt   = wid & 1;     // row-tile role (stages A and B)
    const int ct   = wid >> 1;    // batch role b^

    // ---- one-time: W23 -> LDS (swizzled: phys_oct = (k>>3) ^ (row&31)) ----
    {
      const int r = tid >> 2, kb = (tid & 3) * 64;
      const int m2 = r >> 3, m3 = r & 7;
      float c3v[8][4];
      #pragma unroll
      for (int r3 = 0; r3 < 8; ++r3)
        #pragma unroll
        for (int n3 = 0; n3 < 4; ++n3)
          c3v[r3][n3] = c3[(r3 * 8 + m3) * 4 + n3];
      for (int j = 0; j < 64; ++j) {
        const int k = kb + j;
        const int n2 = k >> 5, n3 = (k >> 3) & 3, r2 = k & 7;
        float s = 0.f;
        #pragma unroll
        for (int r3 = 0; r3 < 8; ++r3)
          s += c2[(r2 * 8 + m2) * 64 + r3 * 8 + n2] * c3v[r3][n3];
        w23l[r * 256 + (((k >> 3) ^ (r & 31)) << 3) + (k & 7)] = (__bf16)s;
      }
    }

    // ---- one-time: W01 A-frags in registers (wave holds its rt slice) ----
    // w01f[m0][kt][j] = W01[m0][rt*32+c32][kt*16+hh*8+j]
    bf16x8 w01f[8][2];
    {
      const int row = rt * 32 + c32, m1 = row >> 3, r2w = row & 7;
      float c1row[8][8];
      #pragma unroll
      for (int r1 = 0; r1 < 8; ++r1)
        #pragma unroll
        for (int n1 = 0; n1 < 8; ++n1)
          c1row[r1][n1] = c1[(r1 * 8 + m1) * 64 + r2w * 8 + n1];
      for (int m0 = 0; m0 < 8; ++m0) {
        #pragma unroll
        for (int kt = 0; kt < 2; ++kt) {
          const int n0 = kt * 2 + hh;
          #pragma unroll
          for (int j = 0; j < 8; ++j) {
            float s = 0.f;
            #pragma unroll
            for (int r1 = 0; r1 < 8; ++r1)
              s += c0[m0 * 32 + r1 * 4 + n0] * c1row[r1][j];
            w01f[m0][kt][j] = (__bf16)s;
          }
        }
      }
    }

    for (int it = 0; it < 8; ++it) {
      const int b0 = (blockIdx.x * 8 + it) * 2;

      // ---- stage x -> Xt[col=(b^*32 + n2n3)][k=n0*8+n1], oct ^= col&3 ----
      {
        const int bsel = tid >> 7, col = tid & 31, k0q = (tid >> 5) & 3;
        const float* xp = x + (size_t)(b0 + bsel) * 1024 + col;
        bf16x8 v;
        #pragma unroll
        for (int j = 0; j < 8; ++j) v[j] = (__bf16)xp[(k0q * 8 + j) * 32];
        *(bf16x8*)&xt[(bsel * 32 + col) * 32 + ((k0q ^ (col & 3)) << 3)] = v;
      }
      __syncthreads();

      // hoisted stage-A B-frags (same for both quads)
      bf16x8 xf[2];
      #pragma unroll
      for (int kt = 0; kt < 2; ++kt)
        xf[kt] = *(const bf16x8*)
          &xt[(ct * 32 + c32) * 32 + (((kt * 2 + hh) ^ (c32 & 3)) << 3)];

      #pragma unroll
      for (int q = 0; q < 2; ++q) {
        // ---- stage A: 4 m0 x (32x32, K=32) ----
        #pragma unroll
        for (int m0h = 0; m0h < 4; ++m0h) {
          f32x16 acc = {};
          acc = MFMA32(w01f[q * 4 + m0h][0], xf[0], acc);
          acc = MFMA32(w01f[q * 4 + m0h][1], xf[1], acc);
          // D row = rt*32 + 8p + 4hh + i -> m1 = rt*4+p, r2 = 4hh+i
          // Hb[cl=(ct*32 + m0h*8 + m1)][k=c32*8 + 4hh + i], oct ^= cl&31
          #pragma unroll
          for (int p = 0; p < 4; ++p) {
            bf16x4 o;
            #pragma unroll
            for (int i = 0; i < 4; ++i) o[i] = (__bf16)acc[p * 4 + i];
            const int cl = ct * 32 + m0h * 8 + rt * 4 + p;
            *(bf16x4*)&hb[cl * 256 + ((c32 ^ (cl & 31)) << 3) + hh * 4] = o;
          }
        }
        __syncthreads();

        // ---- stage B: (32x32, K=256), wave tile = (rt, ct) ----
        const __bf16* arow = &w23l[(rt * 32 + c32) * 256];
        const __bf16* brow = &hb[(ct * 32 + c32) * 256];
        f32x16 acc2 = {};
        #pragma unroll
        for (int kt = 0; kt < 16; ++kt) {
          const int op = ((kt * 2 + hh) ^ c32) << 3;
          const bf16x8 af = *(const bf16x8*)&arow[op];
          const bf16x8 bf = *(const bf16x8*)&brow[op];
          acc2 = MFMA32(af, bf, acc2);
        }

        // ---- epilogue: D row = rt*32+8p+4hh+i -> m2 = rt*4+p, m3 = 4hh+i
        //      col = ct*32+c32 -> b^ = ct, m0^ = c32>>3, m1 = c32&7
        const size_t ybase = (size_t)(b0 + ct) * 4096;
        const int boff = (q * 4 + (c32 >> 3)) * 512 + (c32 & 7) * 64 + hh * 4;
        #pragma unroll
        for (int p = 0; p < 4; ++p) {
          const int off = boff + (rt * 4 + p) * 8;
          const f32x4 bv = *(const f32x4*)&bias[off];
          f32x4 o;
          #pragma unroll
          for (int i = 0; i < 4; ++i) o[i] = acc2[p * 4 + i] + bv[i];
          *(f32x4*)&y[ybase + off] = o;
        }
        __syncthreads();
      }
    }
}

extern "C" void kernel_launch(void* const* d_in, const int* in_sizes, int n_in,
                              void* d_out, int out_size, void* d_ws, size_t ws_size,
                              hipStream_t stream) {
    const float* x    = (const float*)d_in[0];
    const float* c0   = (const float*)d_in[1];
    const float* c1   = (const float*)d_in[2];
    const float* c2   = (const float*)d_in[3];
    const float* c3   = (const float*)d_in[4];
    const float* bias = (const float*)d_in[5];
    float* yout = (float*)d_out;
    // persistent: 512 blocks (2/CU, LDS-capped), 8 iters x 2 batches each
    tt_kernel<<<512, 256, 0, stream>>>(x, c0, c1, c2, c3, bias, yout);
}